// Round 19
// baseline (1081.917 us; speedup 1.0000x reference)
//
#include <hip/hip_runtime.h>
#include <hip/hip_bf16.h>
#include <math.h>

#define B_   16
#define S_   512
#define E_   1024
#define H_   16
#define D_   64
#define NL_  6
#define OUT_ 10
#define M_   (B_*S_)

typedef short short8 __attribute__((ext_vector_type(8)));
typedef float f32x4 __attribute__((ext_vector_type(4)));
typedef int   int4v __attribute__((ext_vector_type(4)));
typedef unsigned short ushort4v __attribute__((ext_vector_type(4)));

typedef const __attribute__((address_space(1))) unsigned int* gas1_t;
typedef __attribute__((address_space(3))) unsigned int* las3_t;
#define GLD16(g,l) __builtin_amdgcn_global_load_lds((gas1_t)(g), (las3_t)(l), 16, 0, 0)
#define VMW(n) asm volatile("s_waitcnt vmcnt(" #n ")" ::: "memory")

static __device__ __forceinline__ float bf2f(unsigned short u){
  union { unsigned int i; float f; } v; v.i = ((unsigned int)u) << 16; return v.f;
}
static __device__ __forceinline__ unsigned short f2bf(float f){
  union { float f; unsigned int i; } v; v.f = f;
  unsigned int r = v.i + 0x7fffu + ((v.i >> 16) & 1u);
  return (unsigned short)(r >> 16);
}
static __device__ __forceinline__ f32x4 mfma16(short8 a, short8 b, f32x4 c){
  return __builtin_amdgcn_mfma_f32_16x16x32_bf16(a, b, c, 0, 0, 0);
}

// ---------------- code writer (f32 output) ----------------
__global__ __launch_bounds__(192)
void code_k(float* __restrict__ out, float code)
{
  int t = threadIdx.x;
  if (t < B_*OUT_) out[t] = code;
}

// ---------------- weight transpose + f32->bf16: wT[n][k] = bf16(w[k][n]) ----------------
__global__ __launch_bounds__(256)
void transpose_k(const float* __restrict__ w0, const float* __restrict__ w1,
                 const float* __restrict__ w2, const float* __restrict__ w3,
                 unsigned short* __restrict__ wT)
{
  const float* w = blockIdx.z==0 ? w0 : blockIdx.z==1 ? w1 : blockIdx.z==2 ? w2 : w3;
  unsigned short* o = wT + (size_t)blockIdx.z * E_ * E_;
  __shared__ unsigned short tl[64][65];
  int n0 = blockIdx.x*64, k0 = blockIdx.y*64;
  int tx = threadIdx.x, ty = threadIdx.y;
  #pragma unroll
  for (int i = 0; i < 16; ++i)
    tl[ty + 4*i][tx] = f2bf(w[(size_t)(k0 + ty + 4*i)*E_ + n0 + tx]);
  __syncthreads();
  #pragma unroll
  for (int i = 0; i < 16; ++i)
    o[(size_t)(n0 + ty + 4*i)*E_ + k0 + tx] = tl[tx][ty + 4*i];
}

// ---------------- embedding + positional: x = 2*emb[tok] + pe[b,e] (batch-indexed, faithful) ----------------
__global__ __launch_bounds__(256)
void embed_k(const int* __restrict__ tok, const float* __restrict__ emb,
             float* __restrict__ x, unsigned short* __restrict__ xb)
{
  int row = blockIdx.x;            // b*512+s
  int b = row >> 9;
  int tk = tok[row];
  tk = tk < 0 ? 0 : (tk > 15 ? 15 : tk);
  int e0 = threadIdx.x * 4;
  const float c0 = -9.210340371976184f / (float)E_;   // -ln(10000)/E
  f32x4 ev = *(const f32x4*)&emb[(size_t)tk * E_ + e0];
  f32x4 vv; ushort4v bb;
  #pragma unroll
  for (int i = 0; i < 4; ++i) {
    int e = e0 + i;
    float dv = expf((float)(e & ~1) * c0);
    float arg = (float)b * dv;
    float pe = (e & 1) ? cosf(arg) : sinf(arg);
    float v = 2.0f * ev[i] + pe;
    vv[i] = v; bb[i] = f2bf(v);
  }
  *(f32x4*)&x[(size_t)row*E_ + e0] = vv;
  *(ushort4v*)&xb[(size_t)row*E_ + e0] = bb;
}

// ---------------- 256x256 bf16 MFMA GEMM, 4-phase/K-tile counted-vmcnt ----------------
// BK=64, 512 threads = 8 waves (2 wr x 4 wc), wave tile 128x64 -> acc[8][4].
// Per K-tile: 4 phases x {ds_read | issue load piece | barrier | setprio MFMA x16 | barrier};
// VMW(4) once per tile; tail VMW(0). LDS: A/B double buffer = 128 KB dynamic.
// MODE 0: fused QKV, grid (32,12): wsel=nt>>2 (0=Q,1=K -> [B,H,S,D]; 2=V -> VT[B,H,D,S])
// MODE 1: FC, grid (32,4): bf16 [M][E]
template<int MODE>
__global__ __launch_bounds__(512, 2)
void gemm256_k(const unsigned short* __restrict__ A,
               const unsigned short* __restrict__ WT,
               const float* __restrict__ bq, const float* __restrict__ bk,
               const float* __restrict__ bv,
               unsigned short* __restrict__ out)
{
  extern __shared__ unsigned short SM2[];
  int mt = blockIdx.x, nt = blockIdx.y;
  int wsel = (MODE==0) ? (nt>>2) : 3;
  int ntl  = (MODE==0) ? (nt&3)  : nt;
  const unsigned short* Bp = WT + (MODE==0 ? (size_t)wsel*E_*E_ : (size_t)0) + (size_t)ntl*256*E_;
  const float* bias = (MODE==0) ? (wsel==0 ? bq : (wsel==1 ? bk : bv)) : bq;
  int m0 = mt*256;
  int tid = threadIdx.x, lane = tid&63, wid = tid>>6;
  int wr = wid>>2, wc = wid&3;               // wave tile: rows wr*128+, cols wc*64+
  int lr = lane&15, lk = lane>>4;
  int rl = tid>>3;                           // 0..63 staging row
  int cs = (tid&7) ^ (rl&7);                 // pre-swizzled source chunk (both-sides rule)
  int sw0 = (lk ^ (lr&7)) << 3;              // read-side swizzled chunk offsets
  int sw1 = ((4+lk) ^ (lr&7)) << 3;

  unsigned short* Ab0 = SM2;
  unsigned short* Ab1 = SM2 + 16384;
  unsigned short* Bb0 = SM2 + 32768;
  unsigned short* Bb1 = SM2 + 49152;

  f32x4 acc[8][4] = {};

  auto stA = [&](unsigned short* dst, int kt) {   // 4 loads: rows q*64+rl, q=0..3
    #pragma unroll
    for (int q = 0; q < 4; ++q)
      GLD16(A + (size_t)(m0 + q*64 + rl)*E_ + kt*64 + cs*8, dst + ((q*512 + tid)<<3));
  };
  auto stBh = [&](unsigned short* dst, int kt, int h) {  // 2 loads
    GLD16(Bp + (size_t)(h*128 + rl)*E_ + kt*64 + cs*8,      dst + ((h*1024 + tid)<<3));
    GLD16(Bp + (size_t)(h*128 + 64 + rl)*E_ + kt*64 + cs*8, dst + ((h*1024 + 512 + tid)<<3));
  };

  // prologue: tile 0 -> buffer 0 (8 loads)
  stA(Ab0, 0); stBh(Bb0, 0, 0); stBh(Bb0, 0, 1);

  for (int kt = 0; kt < 16; ++kt) {
    int cur = kt & 1;
    const unsigned short* Ar = cur ? Ab1 : Ab0;
    const unsigned short* Br = cur ? Bb1 : Bb0;
    unsigned short* An = cur ? Ab0 : Ab1;
    unsigned short* Bn = cur ? Bb0 : Bb1;
    short8 bfr[4][2];
    #pragma unroll
    for (int p = 0; p < 4; ++p) {
      short8 af[2][2];
      if (p == 0) {
        // issue next tile's A, wait for THIS tile (4 newest allowed outstanding)
        if (kt < 15) { stA(An, kt+1); VMW(4); }
        else         { VMW(0); }
        __builtin_amdgcn_s_barrier();        // tile kt fully staged for all waves
        #pragma unroll
        for (int i = 0; i < 2; ++i) {
          int row = wr*128 + i*16 + lr;
          af[i][0] = *(const short8*)&Ar[row*64 + sw0];
          af[i][1] = *(const short8*)&Ar[row*64 + sw1];
        }
        #pragma unroll
        for (int ni = 0; ni < 4; ++ni) {
          int row = wc*64 + ni*16 + lr;
          bfr[ni][0] = *(const short8*)&Br[row*64 + sw0];
          bfr[ni][1] = *(const short8*)&Br[row*64 + sw1];
        }
      } else {
        // reads issued before the barrier: drain under barrier slack / other waves' MFMA
        #pragma unroll
        for (int i = 0; i < 2; ++i) {
          int row = wr*128 + (p*2 + i)*16 + lr;
          af[i][0] = *(const short8*)&Ar[row*64 + sw0];
          af[i][1] = *(const short8*)&Ar[row*64 + sw1];
        }
        if (p == 1 && kt < 15) stBh(Bn, kt+1, 0);
        if (p == 2 && kt < 15) stBh(Bn, kt+1, 1);
        __builtin_amdgcn_s_barrier();
      }
      __builtin_amdgcn_s_setprio(1);
      #pragma unroll
      for (int kk = 0; kk < 2; ++kk)
        #pragma unroll
        for (int i = 0; i < 2; ++i)
          #pragma unroll
          for (int ni = 0; ni < 4; ++ni)
            acc[p*2+i][ni] = mfma16(af[i][kk], bfr[ni][kk], acc[p*2+i][ni]);
      __builtin_amdgcn_s_setprio(0);
      __builtin_amdgcn_s_barrier();
    }
  }

  if (MODE == 1 || wsel < 2) {
    // row-major stage Cs[256][272], then 64-col-run coalesced stores
    unsigned short* Cs = SM2;
    #pragma unroll
    for (int ni = 0; ni < 4; ++ni) {
      int n = ntl*256 + wc*64 + ni*16 + lr;
      float bv2 = bias[n];
      #pragma unroll
      for (int mi = 0; mi < 8; ++mi)
        #pragma unroll
        for (int j = 0; j < 4; ++j)
          Cs[(wr*128 + mi*16 + lk*4 + j)*272 + wc*64 + ni*16 + lr] =
            f2bf(acc[mi][ni][j] + bv2);
    }
    __syncthreads();
    #pragma unroll
    for (int it = 0; it < 2; ++it) {
      int id = it*512 + tid;
      int r = id >> 2, qd = id & 3;
      const unsigned short* sp = &Cs[r*272 + qd*64];
      unsigned short* gp;
      if (MODE == 1) {
        gp = out + (size_t)(m0 + r)*E_ + ntl*256 + qd*64;
      } else {
        int m = m0 + r;
        int b = m >> 9, s = m & 511;
        int h = ntl*4 + qd;
        gp = out + (size_t)wsel*M_*E_ + (((size_t)(b*H_ + h)*S_ + s)*D_);
      }
      #pragma unroll
      for (int c = 0; c < 8; ++c)
        *(int4v*)(gp + c*8) = *(const int4v*)(sp + c*8);
    }
  } else {
    // V: transposed stage Ct[256 cols][264], write VT[B,H,D,S]
    unsigned short* Ct = SM2;
    #pragma unroll
    for (int ni = 0; ni < 4; ++ni) {
      int nl = wc*64 + ni*16 + lr;
      float bv2 = bias[ntl*256 + nl];
      #pragma unroll
      for (int mi = 0; mi < 8; ++mi)
        #pragma unroll
        for (int j = 0; j < 4; ++j)
          Ct[nl*264 + wr*128 + mi*16 + lk*4 + j] = f2bf(acc[mi][ni][j] + bv2);
    }
    __syncthreads();
    int b = m0 >> 9, s0 = m0 & 511;
    #pragma unroll
    for (int it = 0; it < 2; ++it) {
      int id = it*512 + tid;
      int nl = id >> 2, mc = id & 3;
      int n = ntl*256 + nl;
      int h = n >> 6, d = n & 63;
      unsigned short* gp = out + (size_t)2*M_*E_ +
                           (((size_t)(b*H_ + h)*D_ + d)*S_ + s0 + mc*64);
      const unsigned short* sp = &Ct[nl*264 + mc*64];
      #pragma unroll
      for (int c = 0; c < 8; ++c)
        *(int4v*)(gp + c*8) = *(const int4v*)(sp + c*8);
    }
  }
}

// ---------------- flash attention: kt-outer, K+V double-buffered in LDS ----------------
// (unchanged — verified passing)
__global__ __launch_bounds__(512, 4)
void attn_k(const unsigned short* __restrict__ Q, const unsigned short* __restrict__ K,
            const unsigned short* __restrict__ VT, unsigned short* __restrict__ O)
{
  extern __shared__ unsigned short SMEM[];
  int bid = blockIdx.x;
  int bh = bid & 255, qh = bid >> 8;
  int tid = threadIdx.x, lane = tid & 63, wid = tid >> 6;
  int lr = lane & 15, lk = lane >> 4;
  const unsigned short* Qb = Q + (size_t)bh * S_ * D_;
  const unsigned short* Kb = K + (size_t)bh * S_ * D_;
  const unsigned short* VTb = VT + (size_t)bh * S_ * D_;
  unsigned short* Pw = SMEM + 32768 + wid * 640;

  int kr  = tid >> 3, kc8 = tid & 7;
  int kcs = kc8 ^ (kr & 7);
  short8 qf[2][2];
  #pragma unroll
  for (int s = 0; s < 2; ++s) {
    int q0 = (qh*2 + s)*128 + wid*16;
    qf[s][0] = *(const short8*)(Qb + (size_t)(q0 + lr)*D_ + lk*8);
    qf[s][1] = *(const short8*)(Qb + (size_t)(q0 + lr)*D_ + 32 + lk*8);
  }
  {
    unsigned short* Kd = SMEM;
    #pragma unroll
    for (int j = 0; j < 2; ++j) {
      int idx = j*512 + tid;
      GLD16(Kb + (size_t)(kr + j*64)*D_ + kcs*8, &Kd[idx*8]);
    }
  }
  {
    unsigned short* Vd = SMEM + 16384;
    #pragma unroll
    for (int j = 0; j < 2; ++j) {
      int idx = j*512 + tid;
      int d = idx >> 4, c16 = idx & 15;
      int cds = c16 ^ (d & 15);
      GLD16(VTb + (size_t)d*S_ + cds*8, &Vd[idx*8]);
    }
  }
  __syncthreads();

  f32x4 oacc[2][4] = {};
  float plsum[2][4] = {{0.f,0.f,0.f,0.f},{0.f,0.f,0.f,0.f}};
  int cur = 0;
  for (int kt = 0; kt < 4; ++kt) {
    if (kt < 3) {
      unsigned short* Kd = SMEM + (cur^1)*8192;
      unsigned short* Vd = SMEM + 16384 + (cur^1)*8192;
      #pragma unroll
      for (int j = 0; j < 2; ++j) {
        int idx = j*512 + tid;
        int r = idx >> 3, c8 = idx & 7;
        GLD16(Kb + (size_t)((kt+1)*128 + r)*D_ + (c8 ^ (r & 7))*8, &Kd[idx*8]);
        int d = idx >> 4, c16 = idx & 15;
        GLD16(VTb + (size_t)d*S_ + (kt+1)*128 + (c16 ^ (d & 15))*8, &Vd[idx*8]);
      }
    }
    const unsigned short* Kl = SMEM + cur*8192;
    const unsigned short* Vl = SMEM + 16384 + cur*8192;
    #pragma unroll
    for (int s = 0; s < 2; ++s) {
      #pragma unroll
      for (int c = 0; c < 4; ++c) {
        f32x4 s0 = {}, s1 = {};
        {
          const unsigned short* kr0 = &Kl[((2*c)*16 + lr)*64];
          const unsigned short* kr1 = &Kl[((2*c+1)*16 + lr)*64];
          int a0 = ((lk     ^ (lr & 7)))*8;
          int a1 = (((4+lk) ^ (lr & 7)))*8;
          s0 = mfma16(qf[s][0], *(const short8*)(kr0 + a0), s0);
          s0 = mfma16(qf[s][1], *(const short8*)(kr0 + a1), s0);
          s1 = mfma16(qf[s][0], *(const short8*)(kr1 + a0), s1);
          s1 = mfma16(qf[s][1], *(const short8*)(kr1 + a1), s1);
        }
        #pragma unroll
        for (int j = 0; j < 4; ++j) {
          s0[j] = __expf(s0[j] * 0.125f);
          s1[j] = __expf(s1[j] * 0.125f);
          plsum[s][j] += s0[j] + s1[j];
        }
        #pragma unroll
        for (int j = 0; j < 4; ++j) {
          Pw[(lk*4 + j)*40 + lr]      = f2bf(s0[j]);
          Pw[(lk*4 + j)*40 + 16 + lr] = f2bf(s1[j]);
        }
        asm volatile("s_waitcnt lgkmcnt(0)" ::: "memory");
        short8 pf = *(const short8*)&Pw[lr*40 + lk*8];
        #pragma unroll
        for (int dt = 0; dt < 4; ++dt) {
          int drow = dt*16 + lr;
          short8 vf = *(const short8*)&Vl[drow*128 + (((c*4 + lk) ^ lr))*8];
          oacc[s][dt] = mfma16(pf, vf, oacc[s][dt]);
        }
      }
    }
    __syncthreads();
    cur ^= 1;
  }
  #pragma unroll
  for (int s = 0; s < 2; ++s) {
    float lsum[4];
    #pragma unroll
    for (int j = 0; j < 4; ++j) {
      float t = plsum[s][j];
      #pragma unroll
      for (int m = 1; m < 16; m <<= 1) t += __shfl_xor(t, m);
      lsum[j] = t;
    }
    int q0 = (qh*2 + s)*128 + wid*16;
    #pragma unroll
    for (int dt = 0; dt < 4; ++dt)
      #pragma unroll
      for (int j = 0; j < 4; ++j)
        O[(size_t)bh*S_*D_ + (size_t)(q0 + lk*4 + j)*D_ + dt*16 + lr] =
          f2bf(oacc[s][dt][j] / lsum[j]);
  }
}

// ---------------- residual + layernorm (bf16 g input, f32 stream + bf16 copy) ----------------
template<bool PERM>
__global__ __launch_bounds__(256)
void ln_k(const unsigned short* __restrict__ g, float* __restrict__ x,
          unsigned short* __restrict__ xb,
          const float* __restrict__ gamma, const float* __restrict__ beta)
{
  int row = blockIdx.x;
  int tid = threadIdx.x;
  int e0 = tid * 4;
  ushort4v gu;
  if (PERM) {
    int b = row >> 9, s = row & 511;
    int h = e0 >> 6, d = e0 & 63;
    gu = *(const ushort4v*)&g[(((size_t)(b*H_ + h)*S_) + s)*D_ + d];
  } else {
    gu = *(const ushort4v*)&g[(size_t)row*E_ + e0];
  }
  f32x4 xv = *(const f32x4*)&x[(size_t)row*E_ + e0];
  f32x4 v;
  #pragma unroll
  for (int i = 0; i < 4; ++i) v[i] = bf2f(gu[i]) + xv[i];
  float sum = v[0]+v[1]+v[2]+v[3];
  float sq  = v[0]*v[0]+v[1]*v[1]+v[2]*v[2]+v[3]*v[3];
  #pragma unroll
  for (int m = 1; m < 64; m <<= 1) { sum += __shfl_xor(sum, m); sq += __shfl_xor(sq, m); }
  __shared__ float red[2][4];
  int lane = tid & 63, wid = tid >> 6;
  if (lane == 0) { red[0][wid] = sum; red[1][wid] = sq; }
  __syncthreads();
  float ts = red[0][0]+red[0][1]+red[0][2]+red[0][3];
  float tq = red[1][0]+red[1][1]+red[1][2]+red[1][3];
  float mu = ts * (1.0f/E_);
  float var = tq * (1.0f/E_) - mu*mu;
  float rsq = rsqrtf(var + 1e-5f);
  f32x4 y; ushort4v yb;
  #pragma unroll
  for (int i = 0; i < 4; ++i) {
    float t = (v[i]-mu)*rsq*gamma[e0+i] + beta[e0+i];
    y[i] = t; yb[i] = f2bf(t);
  }
  *(f32x4*)&x[(size_t)row*E_ + e0] = y;
  *(ushort4v*)&xb[(size_t)row*E_ + e0] = yb;
}

// ---------------- output head (all f32, exact) ----------------
__global__ __launch_bounds__(256)
void outp_k(const float* __restrict__ x, const float* __restrict__ wout,
            float* __restrict__ part)
{
  int b = blockIdx.y;
  int chunk = blockIdx.x;
  int tid = threadIdx.x;
  float acc[OUT_] = {};
  const float* xr = x + (size_t)b * S_ * E_;
  for (int j = 0; j < 32; ++j) {
    int k = chunk*8192 + j*256 + tid;
    float xv = xr[k];
    const float* wr = wout + (size_t)k * OUT_;
    #pragma unroll
    for (int o = 0; o < OUT_; ++o) acc[o] += xv * wr[o];
  }
  #pragma unroll
  for (int o = 0; o < OUT_; ++o)
    #pragma unroll
    for (int m = 1; m < 64; m <<= 1) acc[o] += __shfl_xor(acc[o], m);
  __shared__ float red[4][OUT_];
  int lane = tid & 63, wid = tid >> 6;
  if (lane == 0) {
    #pragma unroll
    for (int o = 0; o < OUT_; ++o) red[wid][o] = acc[o];
  }
  __syncthreads();
  if (tid < OUT_) {
    float s = red[0][tid] + red[1][tid] + red[2][tid] + red[3][tid];
    part[((size_t)chunk*B_ + b)*OUT_ + tid] = s;
  }
}

__global__ __launch_bounds__(192)
void outred_k(const float* __restrict__ part, const float* __restrict__ bout,
              float* __restrict__ out)
{
  int t = threadIdx.x;
  if (t < B_*OUT_) {
    int b = t / OUT_, o = t % OUT_;
    float s = 0.f;
    for (int c = 0; c < 64; ++c) s += part[((size_t)c*B_ + b)*OUT_ + o];
    s += bout[o];
    out[t] = s;
  }
}

extern "C" void kernel_launch(void* const* d_in, const int* in_sizes, int n_in,
                              void* d_out, int out_size, void* d_ws, size_t ws_size,
                              hipStream_t stream)
{
  (void)out_size;
  float* outb = (float*)d_out;

  static const int expect[14] = {8192, 16384, 1048576, 1024, 1048576, 1024,
                                 1048576, 1024, 1048576, 1024, 1024, 1024,
                                 5242880, 10};
  if (n_in != 14) { code_k<<<dim3(1), dim3(192), 0, stream>>>(outb, 9000.0f); return; }
  for (int i = 0; i < 14; ++i)
    if (in_sizes[i] != expect[i]) {
      code_k<<<dim3(1), dim3(192), 0, stream>>>(outb, 5000.0f + 100.0f*i); return;
    }

  const int* tok = (const int*)d_in[0];
  const float* emb  = (const float*)d_in[1];
  const float* wq   = (const float*)d_in[2];
  const float* bq   = (const float*)d_in[3];
  const float* wk   = (const float*)d_in[4];
  const float* bk   = (const float*)d_in[5];
  const float* wv   = (const float*)d_in[6];
  const float* bv   = (const float*)d_in[7];
  const float* wfc  = (const float*)d_in[8];
  const float* bfc  = (const float*)d_in[9];
  const float* gam  = (const float*)d_in[10];
  const float* bet  = (const float*)d_in[11];
  const float* wout = (const float*)d_in[12];
  const float* bout = (const float*)d_in[13];

  char* ws = (char*)d_ws;
  size_t off = 0;
  unsigned short* wT = (unsigned short*)(ws + off); off += (size_t)4*E_*E_*2;
  float* x  = (float*)(ws + off);                   off += (size_t)M_*E_*4;
  unsigned short* xb = (unsigned short*)(ws + off); off += (size_t)M_*E_*2;
  unsigned short* qkvb = (unsigned short*)(ws + off); off += (size_t)3*M_*E_*2;
  unsigned short* gb = (unsigned short*)(ws + off); off += (size_t)M_*E_*2;
  float* part = (float*)(ws + off);                 off += (size_t)64*B_*OUT_*4;
  if (off > ws_size) { code_k<<<dim3(1), dim3(192), 0, stream>>>(outb, 9500.0f); return; }

  transpose_k<<<dim3(16,16,4), dim3(64,4), 0, stream>>>(wq, wk, wv, wfc, wT);
  embed_k<<<dim3(M_), dim3(256), 0, stream>>>(tok, emb, x, xb);
  unsigned short* qb = qkvb;
  unsigned short* kb = qkvb + (size_t)M_*E_;
  unsigned short* vb = qkvb + (size_t)2*M_*E_;   // VT [B,H,D,S]
  for (int l = 0; l < NL_; ++l) {
    gemm256_k<0><<<dim3(32,12), dim3(512), 147456, stream>>>(xb, wT, bq, bk, bv, qkvb);
    attn_k<<<dim3(512), dim3(512), 75776, stream>>>(qb, kb, vb, gb);
    ln_k<true><<<dim3(M_), dim3(256), 0, stream>>>(gb, x, xb, gam, bet);
    gemm256_k<1><<<dim3(32,4), dim3(512), 147456, stream>>>(xb, wT + (size_t)3*E_*E_, bfc, bfc, bfc, gb);
    ln_k<false><<<dim3(M_), dim3(256), 0, stream>>>(gb, x, xb, gam, bet);
  }
  outp_k<<<dim3(64,B_), dim3(256), 0, stream>>>(x, wout, part);
  outred_k<<<dim3(1), dim3(192), 0, stream>>>(part, bout, outb);
}

// Round 20
// 983.078 us; speedup vs baseline: 1.1005x; 1.1005x over previous
//
#include <hip/hip_runtime.h>
#include <hip/hip_bf16.h>
#include <math.h>

#define B_   16
#define S_   512
#define E_   1024
#define H_   16
#define D_   64
#define NL_  6
#define OUT_ 10
#define M_   (B_*S_)

typedef short short8 __attribute__((ext_vector_type(8)));
typedef float f32x4 __attribute__((ext_vector_type(4)));
typedef int   int4v __attribute__((ext_vector_type(4)));
typedef unsigned short ushort4v __attribute__((ext_vector_type(4)));

typedef const __attribute__((address_space(1))) unsigned int* gas1_t;
typedef __attribute__((address_space(3))) unsigned int* las3_t;
#define GLD16(g,l) __builtin_amdgcn_global_load_lds((gas1_t)(g), (las3_t)(l), 16, 0, 0)

static __device__ __forceinline__ float bf2f(unsigned short u){
  union { unsigned int i; float f; } v; v.i = ((unsigned int)u) << 16; return v.f;
}
static __device__ __forceinline__ unsigned short f2bf(float f){
  union { float f; unsigned int i; } v; v.f = f;
  unsigned int r = v.i + 0x7fffu + ((v.i >> 16) & 1u);
  return (unsigned short)(r >> 16);
}
static __device__ __forceinline__ f32x4 mfma16(short8 a, short8 b, f32x4 c){
  return __builtin_amdgcn_mfma_f32_16x16x32_bf16(a, b, c, 0, 0, 0);
}

// ---------------- code writer (f32 output) ----------------
__global__ __launch_bounds__(192)
void code_k(float* __restrict__ out, float code)
{
  int t = threadIdx.x;
  if (t < B_*OUT_) out[t] = code;
}

// ---------------- weight transpose + f32->bf16: wT[n][k] = bf16(w[k][n]) ----------------
__global__ __launch_bounds__(256)
void transpose_k(const float* __restrict__ w0, const float* __restrict__ w1,
                 const float* __restrict__ w2, const float* __restrict__ w3,
                 unsigned short* __restrict__ wT)
{
  const float* w = blockIdx.z==0 ? w0 : blockIdx.z==1 ? w1 : blockIdx.z==2 ? w2 : w3;
  unsigned short* o = wT + (size_t)blockIdx.z * E_ * E_;
  __shared__ unsigned short tl[64][65];
  int n0 = blockIdx.x*64, k0 = blockIdx.y*64;
  int tx = threadIdx.x, ty = threadIdx.y;
  #pragma unroll
  for (int i = 0; i < 16; ++i)
    tl[ty + 4*i][tx] = f2bf(w[(size_t)(k0 + ty + 4*i)*E_ + n0 + tx]);
  __syncthreads();
  #pragma unroll
  for (int i = 0; i < 16; ++i)
    o[(size_t)(n0 + ty + 4*i)*E_ + k0 + tx] = tl[tx][ty + 4*i];
}

// ---------------- embedding + positional: x = 2*emb[tok] + pe[b,e]; bf16 out ----------------
__global__ __launch_bounds__(256)
void embed_k(const int* __restrict__ tok, const float* __restrict__ emb,
             unsigned short* __restrict__ x)
{
  int row = blockIdx.x;            // b*512+s
  int b = row >> 9;
  int tk = tok[row];
  tk = tk < 0 ? 0 : (tk > 15 ? 15 : tk);
  int e0 = threadIdx.x * 4;
  const float c0 = -9.210340371976184f / (float)E_;   // -ln(10000)/E
  f32x4 ev = *(const f32x4*)&emb[(size_t)tk * E_ + e0];
  ushort4v bb;
  #pragma unroll
  for (int i = 0; i < 4; ++i) {
    int e = e0 + i;
    float dv = expf((float)(e & ~1) * c0);
    float arg = (float)b * dv;
    float pe = (e & 1) ? cosf(arg) : sinf(arg);
    bb[i] = f2bf(2.0f * ev[i] + pe);
  }
  *(ushort4v*)&x[(size_t)row*E_ + e0] = bb;
}

// ---------------- 128x128 bf16 MFMA GEMM, BT = [N][K], T2 XOR-swizzled LDS ----------------
// MODE 0: QK (grid.y=16): wsel=nyt>>3 (0=Q,1=K), writes bf16 [B,H,S,D] at outq+wsel*M*E
// MODE 2: V  (grid.y=8):  writes TRANSPOSED bf16 [B,H,D,S] at outq
// MODE 1: FC (grid.y=8):  writes bf16 [M][E] at outq
template<int MODE>
__global__ __launch_bounds__(256)
void gemm_bt_k(const unsigned short* __restrict__ A,
               const unsigned short* __restrict__ BT,
               const float* __restrict__ biasA, const float* __restrict__ biasB,
               unsigned short* __restrict__ outq)
{
  __shared__ alignas(16) unsigned short SM[(MODE==2) ? 17408 : 16384];
  unsigned short* Al = SM;
  unsigned short* Bl = SM + 8192;
  int mt = blockIdx.x;
  int nyt = blockIdx.y;
  int wsel = (MODE == 0) ? (nyt >> 3) : 0;
  int nt   = (MODE == 0) ? (nyt & 7) : nyt;
  const unsigned short* Bp = BT + (size_t)wsel * E_ * E_ + (size_t)nt * 128 * E_;
  const float* bias = (MODE == 0) ? (wsel == 0 ? biasA : biasB) : biasA;
  int tid = threadIdx.x;
  int lane = tid & 63, wid = tid >> 6;
  int wr = wid >> 1, wc = wid & 1;
  int m0 = mt * 128;
  int lr = lane & 15, lk = lane >> 4;
  int lx = lr & 7;
  int c8 = tid & 7;
  int rbase = tid >> 3;                  // r = j*32 + rbase
  int c8s = c8 ^ (rbase & 7);
  f32x4 acc[4][4] = {};
  for (int kt = 0; kt < E_/64; ++kt) {
    #pragma unroll
    for (int j = 0; j < 4; ++j) {
      int r = j*32 + rbase;
      int idx = j*256 + tid;
      GLD16(A + (size_t)(m0 + r)*E_ + kt*64 + c8s*8, &Al[idx*8]);
      GLD16(Bp + (size_t)r*E_ + kt*64 + c8s*8, &Bl[idx*8]);
    }
    __syncthreads();
    #pragma unroll
    for (int kk = 0; kk < 2; ++kk) {
      int sA = ((kk*4 + lk) ^ lx) * 8;
      short8 af[4], bfr[4];
      #pragma unroll
      for (int mi = 0; mi < 4; ++mi)
        af[mi] = *(const short8*)&Al[(wr*64 + mi*16 + lr)*64 + sA];
      #pragma unroll
      for (int ni = 0; ni < 4; ++ni)
        bfr[ni] = *(const short8*)&Bl[(wc*64 + ni*16 + lr)*64 + sA];
      #pragma unroll
      for (int mi = 0; mi < 4; ++mi)
        #pragma unroll
        for (int ni = 0; ni < 4; ++ni)
          acc[mi][ni] = mfma16(af[mi], bfr[ni], acc[mi][ni]);
    }
    __syncthreads();
  }
  if (MODE == 2) {
    unsigned short* Ct = SM;
    #pragma unroll
    for (int ni = 0; ni < 4; ++ni) {
      int nl = wc*64 + ni*16 + lr;
      float bv = bias[nt*128 + nl];
      #pragma unroll
      for (int mi = 0; mi < 4; ++mi)
        #pragma unroll
        for (int j = 0; j < 4; ++j)
          Ct[nl*136 + wr*64 + mi*16 + lk*4 + j] = f2bf(acc[mi][ni][j] + bv);
    }
    __syncthreads();
    int dl = tid >> 1, half = tid & 1;
    int h = nt*2 + (dl >> 6), d = dl & 63;
    int bb = m0 >> 9, s0 = (m0 & 511) + half*64;
    unsigned short* gp = outq + (((size_t)(bb*H_ + h)*D_ + d)*S_ + s0);
    #pragma unroll
    for (int c = 0; c < 8; ++c)
      *(int4v*)(gp + c*8) = *(const int4v*)&Ct[dl*136 + half*64 + c*8];
  } else {
    unsigned short* Cl = SM;
    #pragma unroll
    for (int ni = 0; ni < 4; ++ni) {
      int n = nt*128 + wc*64 + ni*16 + lr;
      float bv = bias[n];
      #pragma unroll
      for (int mi = 0; mi < 4; ++mi)
        #pragma unroll
        for (int j = 0; j < 4; ++j)
          Cl[(wr*64 + mi*16 + lk*4 + j)*128 + wc*64 + ni*16 + lr] =
            f2bf(acc[mi][ni][j] + bv);
    }
    __syncthreads();
    int r = tid >> 1, half = tid & 1;
    int m = m0 + r;
    unsigned short* gp;
    if (MODE == 0) {
      int bb = m >> 9, s = m & 511;
      int h = nt*2 + half;
      gp = outq + (size_t)wsel*M_*E_ + (((size_t)(bb*H_ + h)*S_ + s)*D_);
    } else {
      gp = outq + (size_t)m*E_ + nt*128 + half*64;
    }
    const unsigned short* sp = &Cl[r*128 + half*64];
    #pragma unroll
    for (int c = 0; c < 8; ++c)
      *(int4v*)(gp + c*8) = *(const int4v*)(sp + c*8);
  }
}

// ---------------- flash attention: kt-outer, K+V double-buffered in LDS ----------------
// (round-15/19 version — verified passing)
__global__ __launch_bounds__(512, 4)
void attn_k(const unsigned short* __restrict__ Q, const unsigned short* __restrict__ K,
            const unsigned short* __restrict__ VT, unsigned short* __restrict__ O)
{
  extern __shared__ unsigned short SMEM[];
  int bid = blockIdx.x;
  int bh = bid & 255, qh = bid >> 8;
  int tid = threadIdx.x, lane = tid & 63, wid = tid >> 6;
  int lr = lane & 15, lk = lane >> 4;
  const unsigned short* Qb = Q + (size_t)bh * S_ * D_;
  const unsigned short* Kb = K + (size_t)bh * S_ * D_;
  const unsigned short* VTb = VT + (size_t)bh * S_ * D_;
  unsigned short* Pw = SMEM + 32768 + wid * 640;

  int kr  = tid >> 3, kc8 = tid & 7;
  int kcs = kc8 ^ (kr & 7);
  short8 qf[2][2];
  #pragma unroll
  for (int s = 0; s < 2; ++s) {
    int q0 = (qh*2 + s)*128 + wid*16;
    qf[s][0] = *(const short8*)(Qb + (size_t)(q0 + lr)*D_ + lk*8);
    qf[s][1] = *(const short8*)(Qb + (size_t)(q0 + lr)*D_ + 32 + lk*8);
  }
  {
    unsigned short* Kd = SMEM;
    #pragma unroll
    for (int j = 0; j < 2; ++j) {
      int idx = j*512 + tid;
      GLD16(Kb + (size_t)(kr + j*64)*D_ + kcs*8, &Kd[idx*8]);
    }
  }
  {
    unsigned short* Vd = SMEM + 16384;
    #pragma unroll
    for (int j = 0; j < 2; ++j) {
      int idx = j*512 + tid;
      int d = idx >> 4, c16 = idx & 15;
      int cds = c16 ^ (d & 15);
      GLD16(VTb + (size_t)d*S_ + cds*8, &Vd[idx*8]);
    }
  }
  __syncthreads();

  f32x4 oacc[2][4] = {};
  float plsum[2][4] = {{0.f,0.f,0.f,0.f},{0.f,0.f,0.f,0.f}};
  int cur = 0;
  for (int kt = 0; kt < 4; ++kt) {
    if (kt < 3) {
      unsigned short* Kd = SMEM + (cur^1)*8192;
      unsigned short* Vd = SMEM + 16384 + (cur^1)*8192;
      #pragma unroll
      for (int j = 0; j < 2; ++j) {
        int idx = j*512 + tid;
        int r = idx >> 3, c8 = idx & 7;
        GLD16(Kb + (size_t)((kt+1)*128 + r)*D_ + (c8 ^ (r & 7))*8, &Kd[idx*8]);
        int d = idx >> 4, c16 = idx & 15;
        GLD16(VTb + (size_t)d*S_ + (kt+1)*128 + (c16 ^ (d & 15))*8, &Vd[idx*8]);
      }
    }
    const unsigned short* Kl = SMEM + cur*8192;
    const unsigned short* Vl = SMEM + 16384 + cur*8192;
    #pragma unroll
    for (int s = 0; s < 2; ++s) {
      #pragma unroll
      for (int c = 0; c < 4; ++c) {
        f32x4 s0 = {}, s1 = {};
        {
          const unsigned short* kr0 = &Kl[((2*c)*16 + lr)*64];
          const unsigned short* kr1 = &Kl[((2*c+1)*16 + lr)*64];
          int a0 = ((lk     ^ (lr & 7)))*8;
          int a1 = (((4+lk) ^ (lr & 7)))*8;
          s0 = mfma16(qf[s][0], *(const short8*)(kr0 + a0), s0);
          s0 = mfma16(qf[s][1], *(const short8*)(kr0 + a1), s0);
          s1 = mfma16(qf[s][0], *(const short8*)(kr1 + a0), s1);
          s1 = mfma16(qf[s][1], *(const short8*)(kr1 + a1), s1);
        }
        #pragma unroll
        for (int j = 0; j < 4; ++j) {
          s0[j] = __expf(s0[j] * 0.125f);
          s1[j] = __expf(s1[j] * 0.125f);
          plsum[s][j] += s0[j] + s1[j];
        }
        #pragma unroll
        for (int j = 0; j < 4; ++j) {
          Pw[(lk*4 + j)*40 + lr]      = f2bf(s0[j]);
          Pw[(lk*4 + j)*40 + 16 + lr] = f2bf(s1[j]);
        }
        asm volatile("s_waitcnt lgkmcnt(0)" ::: "memory");
        short8 pf = *(const short8*)&Pw[lr*40 + lk*8];
        #pragma unroll
        for (int dt = 0; dt < 4; ++dt) {
          int drow = dt*16 + lr;
          short8 vf = *(const short8*)&Vl[drow*128 + (((c*4 + lk) ^ lr))*8];
          oacc[s][dt] = mfma16(pf, vf, oacc[s][dt]);
        }
      }
    }
    __syncthreads();
    cur ^= 1;
  }
  #pragma unroll
  for (int s = 0; s < 2; ++s) {
    float lsum[4];
    #pragma unroll
    for (int j = 0; j < 4; ++j) {
      float t = plsum[s][j];
      #pragma unroll
      for (int m = 1; m < 16; m <<= 1) t += __shfl_xor(t, m);
      lsum[j] = t;
    }
    int q0 = (qh*2 + s)*128 + wid*16;
    #pragma unroll
    for (int dt = 0; dt < 4; ++dt)
      #pragma unroll
      for (int j = 0; j < 4; ++j)
        O[(size_t)bh*S_*D_ + (size_t)(q0 + lk*4 + j)*D_ + dt*16 + lr] =
          f2bf(oacc[s][dt][j] / lsum[j]);
  }
}

// ---------------- residual + layernorm: all-bf16 stream, f32 internal ----------------
template<bool PERM>
__global__ __launch_bounds__(256)
void ln_k(const unsigned short* __restrict__ g, unsigned short* __restrict__ x,
          const float* __restrict__ gamma, const float* __restrict__ beta)
{
  int row = blockIdx.x;
  int tid = threadIdx.x;
  int e0 = tid * 4;
  ushort4v gu;
  if (PERM) {
    int b = row >> 9, s = row & 511;
    int h = e0 >> 6, d = e0 & 63;
    gu = *(const ushort4v*)&g[(((size_t)(b*H_ + h)*S_) + s)*D_ + d];
  } else {
    gu = *(const ushort4v*)&g[(size_t)row*E_ + e0];
  }
  ushort4v xu = *(const ushort4v*)&x[(size_t)row*E_ + e0];
  f32x4 v;
  #pragma unroll
  for (int i = 0; i < 4; ++i) v[i] = bf2f(gu[i]) + bf2f(xu[i]);
  float sum = v[0]+v[1]+v[2]+v[3];
  float sq  = v[0]*v[0]+v[1]*v[1]+v[2]*v[2]+v[3]*v[3];
  #pragma unroll
  for (int m = 1; m < 64; m <<= 1) { sum += __shfl_xor(sum, m); sq += __shfl_xor(sq, m); }
  __shared__ float red[2][4];
  int lane = tid & 63, wid = tid >> 6;
  if (lane == 0) { red[0][wid] = sum; red[1][wid] = sq; }
  __syncthreads();
  float ts = red[0][0]+red[0][1]+red[0][2]+red[0][3];
  float tq = red[1][0]+red[1][1]+red[1][2]+red[1][3];
  float mu = ts * (1.0f/E_);
  float var = tq * (1.0f/E_) - mu*mu;
  float rsq = rsqrtf(var + 1e-5f);
  ushort4v yb;
  #pragma unroll
  for (int i = 0; i < 4; ++i)
    yb[i] = f2bf((v[i]-mu)*rsq*gamma[e0+i] + beta[e0+i]);
  *(ushort4v*)&x[(size_t)row*E_ + e0] = yb;
}

// ---------------- output head (bf16 x input, f32 accum) ----------------
__global__ __launch_bounds__(256)
void outp_k(const unsigned short* __restrict__ x, const float* __restrict__ wout,
            float* __restrict__ part)
{
  int b = blockIdx.y;
  int chunk = blockIdx.x;
  int tid = threadIdx.x;
  float acc[OUT_] = {};
  const unsigned short* xr = x + (size_t)b * S_ * E_;
  for (int j = 0; j < 32; ++j) {
    int k = chunk*8192 + j*256 + tid;
    float xv = bf2f(xr[k]);
    const float* wr = wout + (size_t)k * OUT_;
    #pragma unroll
    for (int o = 0; o < OUT_; ++o) acc[o] += xv * wr[o];
  }
  #pragma unroll
  for (int o = 0; o < OUT_; ++o)
    #pragma unroll
    for (int m = 1; m < 64; m <<= 1) acc[o] += __shfl_xor(acc[o], m);
  __shared__ float red[4][OUT_];
  int lane = tid & 63, wid = tid >> 6;
  if (lane == 0) {
    #pragma unroll
    for (int o = 0; o < OUT_; ++o) red[wid][o] = acc[o];
  }
  __syncthreads();
  if (tid < OUT_) {
    float s = red[0][tid] + red[1][tid] + red[2][tid] + red[3][tid];
    part[((size_t)chunk*B_ + b)*OUT_ + tid] = s;
  }
}

__global__ __launch_bounds__(192)
void outred_k(const float* __restrict__ part, const float* __restrict__ bout,
              float* __restrict__ out)
{
  int t = threadIdx.x;
  if (t < B_*OUT_) {
    int b = t / OUT_, o = t % OUT_;
    float s = 0.f;
    for (int c = 0; c < 64; ++c) s += part[((size_t)c*B_ + b)*OUT_ + o];
    s += bout[o];
    out[t] = s;
  }
}

extern "C" void kernel_launch(void* const* d_in, const int* in_sizes, int n_in,
                              void* d_out, int out_size, void* d_ws, size_t ws_size,
                              hipStream_t stream)
{
  (void)out_size;
  float* outb = (float*)d_out;

  static const int expect[14] = {8192, 16384, 1048576, 1024, 1048576, 1024,
                                 1048576, 1024, 1048576, 1024, 1024, 1024,
                                 5242880, 10};
  if (n_in != 14) { code_k<<<dim3(1), dim3(192), 0, stream>>>(outb, 9000.0f); return; }
  for (int i = 0; i < 14; ++i)
    if (in_sizes[i] != expect[i]) {
      code_k<<<dim3(1), dim3(192), 0, stream>>>(outb, 5000.0f + 100.0f*i); return;
    }

  const int* tok = (const int*)d_in[0];
  const float* emb  = (const float*)d_in[1];
  const float* wq   = (const float*)d_in[2];
  const float* bq   = (const float*)d_in[3];
  const float* wk   = (const float*)d_in[4];
  const float* bk   = (const float*)d_in[5];
  const float* wv   = (const float*)d_in[6];
  const float* bv   = (const float*)d_in[7];
  const float* wfc  = (const float*)d_in[8];
  const float* bfc  = (const float*)d_in[9];
  const float* gam  = (const float*)d_in[10];
  const float* bet  = (const float*)d_in[11];
  const float* wout = (const float*)d_in[12];
  const float* bout = (const float*)d_in[13];

  char* ws = (char*)d_ws;
  size_t off = 0;
  unsigned short* wT = (unsigned short*)(ws + off); off += (size_t)4*E_*E_*2;
  unsigned short* x  = (unsigned short*)(ws + off); off += (size_t)M_*E_*2;
  unsigned short* qkvb = (unsigned short*)(ws + off); off += (size_t)3*M_*E_*2;
  unsigned short* gb = (unsigned short*)(ws + off); off += (size_t)M_*E_*2;
  float* part = (float*)(ws + off);                 off += (size_t)64*B_*OUT_*4;
  if (off > ws_size) { code_k<<<dim3(1), dim3(192), 0, stream>>>(outb, 9500.0f); return; }

  transpose_k<<<dim3(16,16,4), dim3(64,4), 0, stream>>>(wq, wk, wv, wfc, wT);
  embed_k<<<dim3(M_), dim3(256), 0, stream>>>(tok, emb, x);
  unsigned short* qb = qkvb;
  unsigned short* kb = qkvb + (size_t)M_*E_;
  unsigned short* vb = qkvb + (size_t)2*M_*E_;   // VT [B,H,D,S]
  for (int l = 0; l < NL_; ++l) {
    gemm_bt_k<0><<<dim3(64,16), dim3(256), 0, stream>>>(x, wT, bq, bk, qkvb);
    gemm_bt_k<2><<<dim3(64,8),  dim3(256), 0, stream>>>(x, wT + (size_t)2*E_*E_, bv, bv, vb);
    attn_k<<<dim3(512), dim3(512), 75776, stream>>>(qb, kb, vb, gb);
    ln_k<true><<<dim3(M_), dim3(256), 0, stream>>>(gb, x, gam, bet);
    gemm_bt_k<1><<<dim3(64,8), dim3(256), 0, stream>>>(x, wT + (size_t)3*E_*E_, bfc, bfc, gb);
    ln_k<false><<<dim3(M_), dim3(256), 0, stream>>>(gb, x, gam, bet);
  }
  outp_k<<<dim3(64,B_), dim3(256), 0, stream>>>(x, wout, part);
  outred_k<<<dim3(1), dim3(192), 0, stream>>>(part, bout, outb);
}

// Round 21
// 960.918 us; speedup vs baseline: 1.1259x; 1.0231x over previous
//
#include <hip/hip_runtime.h>
#include <hip/hip_bf16.h>
#include <math.h>

#define B_   16
#define S_   512
#define E_   1024
#define H_   16
#define D_   64
#define NL_  6
#define OUT_ 10
#define M_   (B_*S_)

typedef short short8 __attribute__((ext_vector_type(8)));
typedef float f32x4 __attribute__((ext_vector_type(4)));
typedef int   int4v __attribute__((ext_vector_type(4)));
typedef unsigned short ushort4v __attribute__((ext_vector_type(4)));

typedef const __attribute__((address_space(1))) unsigned int* gas1_t;
typedef __attribute__((address_space(3))) unsigned int* las3_t;
#define GLD16(g,l) __builtin_amdgcn_global_load_lds((gas1_t)(g), (las3_t)(l), 16, 0, 0)

static __device__ __forceinline__ float bf2f(unsigned short u){
  union { unsigned int i; float f; } v; v.i = ((unsigned int)u) << 16; return v.f;
}
// native bf16 convert (RNE) — compiler lowers to hw cvt on gfx950 (m240: scalar cast is the fast path)
static __device__ __forceinline__ unsigned short f2bf(float f){
  union { __hip_bfloat16 h; unsigned short u; } v;
  v.h = __float2bfloat16(f);
  return v.u;
}
static __device__ __forceinline__ f32x4 mfma16(short8 a, short8 b, f32x4 c){
  return __builtin_amdgcn_mfma_f32_16x16x32_bf16(a, b, c, 0, 0, 0);
}

// ---------------- code writer (f32 output) ----------------
__global__ __launch_bounds__(192)
void code_k(float* __restrict__ out, float code)
{
  int t = threadIdx.x;
  if (t < B_*OUT_) out[t] = code;
}

// ---------------- weight transpose + f32->bf16: wT[n][k] = bf16(w[k][n]) ----------------
__global__ __launch_bounds__(256)
void transpose_k(const float* __restrict__ w0, const float* __restrict__ w1,
                 const float* __restrict__ w2, const float* __restrict__ w3,
                 unsigned short* __restrict__ wT)
{
  const float* w = blockIdx.z==0 ? w0 : blockIdx.z==1 ? w1 : blockIdx.z==2 ? w2 : w3;
  unsigned short* o = wT + (size_t)blockIdx.z * E_ * E_;
  __shared__ unsigned short tl[64][65];
  int n0 = blockIdx.x*64, k0 = blockIdx.y*64;
  int tx = threadIdx.x, ty = threadIdx.y;
  #pragma unroll
  for (int i = 0; i < 16; ++i)
    tl[ty + 4*i][tx] = f2bf(w[(size_t)(k0 + ty + 4*i)*E_ + n0 + tx]);
  __syncthreads();
  #pragma unroll
  for (int i = 0; i < 16; ++i)
    o[(size_t)(n0 + ty + 4*i)*E_ + k0 + tx] = tl[tx][ty + 4*i];
}

// ---------------- embedding + positional: x = 2*emb[tok] + pe[b,e]; bf16 out ----------------
__global__ __launch_bounds__(256)
void embed_k(const int* __restrict__ tok, const float* __restrict__ emb,
             unsigned short* __restrict__ x)
{
  int row = blockIdx.x;            // b*512+s
  int b = row >> 9;
  int tk = tok[row];
  tk = tk < 0 ? 0 : (tk > 15 ? 15 : tk);
  int e0 = threadIdx.x * 4;
  const float c0 = -9.210340371976184f / (float)E_;   // -ln(10000)/E
  f32x4 ev = *(const f32x4*)&emb[(size_t)tk * E_ + e0];
  ushort4v bb;
  #pragma unroll
  for (int i = 0; i < 4; ++i) {
    int e = e0 + i;
    float dv = expf((float)(e & ~1) * c0);
    float arg = (float)b * dv;
    float pe = (e & 1) ? cosf(arg) : sinf(arg);
    bb[i] = f2bf(2.0f * ev[i] + pe);
  }
  *(ushort4v*)&x[(size_t)row*E_ + e0] = bb;
}

// ---------------- 128x128 bf16 MFMA GEMM, BT = [N][K], T2 XOR-swizzled LDS ----------------
// MODE 0: QK (grid.y=16): wsel=nyt>>3 (0=Q,1=K), writes bf16 [B,H,S,D] at outq+wsel*M*E
// MODE 2: V  (grid.y=8):  writes TRANSPOSED bf16 [B,H,D,S] at outq
// MODE 1: FC (grid.y=8):  writes bf16 [M][E] at outq
template<int MODE>
__global__ __launch_bounds__(256)
void gemm_bt_k(const unsigned short* __restrict__ A,
               const unsigned short* __restrict__ BT,
               const float* __restrict__ biasA, const float* __restrict__ biasB,
               unsigned short* __restrict__ outq)
{
  __shared__ alignas(16) unsigned short SM[(MODE==2) ? 17408 : 16384];
  unsigned short* Al = SM;
  unsigned short* Bl = SM + 8192;
  int mt = blockIdx.x;
  int nyt = blockIdx.y;
  int wsel = (MODE == 0) ? (nyt >> 3) : 0;
  int nt   = (MODE == 0) ? (nyt & 7) : nyt;
  const unsigned short* Bp = BT + (size_t)wsel * E_ * E_ + (size_t)nt * 128 * E_;
  const float* bias = (MODE == 0) ? (wsel == 0 ? biasA : biasB) : biasA;
  int tid = threadIdx.x;
  int lane = tid & 63, wid = tid >> 6;
  int wr = wid >> 1, wc = wid & 1;
  int m0 = mt * 128;
  int lr = lane & 15, lk = lane >> 4;
  int lx = lr & 7;
  int c8 = tid & 7;
  int rbase = tid >> 3;                  // r = j*32 + rbase
  int c8s = c8 ^ (rbase & 7);
  f32x4 acc[4][4] = {};
  for (int kt = 0; kt < E_/64; ++kt) {
    #pragma unroll
    for (int j = 0; j < 4; ++j) {
      int r = j*32 + rbase;
      int idx = j*256 + tid;
      GLD16(A + (size_t)(m0 + r)*E_ + kt*64 + c8s*8, &Al[idx*8]);
      GLD16(Bp + (size_t)r*E_ + kt*64 + c8s*8, &Bl[idx*8]);
    }
    __syncthreads();
    #pragma unroll
    for (int kk = 0; kk < 2; ++kk) {
      int sA = ((kk*4 + lk) ^ lx) * 8;
      short8 af[4], bfr[4];
      #pragma unroll
      for (int mi = 0; mi < 4; ++mi)
        af[mi] = *(const short8*)&Al[(wr*64 + mi*16 + lr)*64 + sA];
      #pragma unroll
      for (int ni = 0; ni < 4; ++ni)
        bfr[ni] = *(const short8*)&Bl[(wc*64 + ni*16 + lr)*64 + sA];
      #pragma unroll
      for (int mi = 0; mi < 4; ++mi)
        #pragma unroll
        for (int ni = 0; ni < 4; ++ni)
          acc[mi][ni] = mfma16(af[mi], bfr[ni], acc[mi][ni]);
    }
    __syncthreads();
  }
  if (MODE == 2) {
    unsigned short* Ct = SM;
    #pragma unroll
    for (int ni = 0; ni < 4; ++ni) {
      int nl = wc*64 + ni*16 + lr;
      float bv = bias[nt*128 + nl];
      #pragma unroll
      for (int mi = 0; mi < 4; ++mi)
        #pragma unroll
        for (int j = 0; j < 4; ++j)
          Ct[nl*136 + wr*64 + mi*16 + lk*4 + j] = f2bf(acc[mi][ni][j] + bv);
    }
    __syncthreads();
    int dl = tid >> 1, half = tid & 1;
    int h = nt*2 + (dl >> 6), d = dl & 63;
    int bb = m0 >> 9, s0 = (m0 & 511) + half*64;
    unsigned short* gp = outq + (((size_t)(bb*H_ + h)*D_ + d)*S_ + s0);
    #pragma unroll
    for (int c = 0; c < 8; ++c)
      *(int4v*)(gp + c*8) = *(const int4v*)&Ct[dl*136 + half*64 + c*8];
  } else {
    unsigned short* Cl = SM;
    #pragma unroll
    for (int ni = 0; ni < 4; ++ni) {
      int n = nt*128 + wc*64 + ni*16 + lr;
      float bv = bias[n];
      #pragma unroll
      for (int mi = 0; mi < 4; ++mi)
        #pragma unroll
        for (int j = 0; j < 4; ++j)
          Cl[(wr*64 + mi*16 + lk*4 + j)*128 + wc*64 + ni*16 + lr] =
            f2bf(acc[mi][ni][j] + bv);
    }
    __syncthreads();
    int r = tid >> 1, half = tid & 1;
    int m = m0 + r;
    unsigned short* gp;
    if (MODE == 0) {
      int bb = m >> 9, s = m & 511;
      int h = nt*2 + half;
      gp = outq + (size_t)wsel*M_*E_ + (((size_t)(bb*H_ + h)*S_ + s)*D_);
    } else {
      gp = outq + (size_t)m*E_ + nt*128 + half*64;
    }
    const unsigned short* sp = &Cl[r*128 + half*64];
    #pragma unroll
    for (int c = 0; c < 8; ++c)
      *(int4v*)(gp + c*8) = *(const int4v*)(sp + c*8);
  }
}

// ---------------- flash attention: kt-outer, K+V double-buffered in LDS ----------------
__global__ __launch_bounds__(512, 4)
void attn_k(const unsigned short* __restrict__ Q, const unsigned short* __restrict__ K,
            const unsigned short* __restrict__ VT, unsigned short* __restrict__ O)
{
  extern __shared__ unsigned short SMEM[];
  int bid = blockIdx.x;
  int bh = bid & 255, qh = bid >> 8;
  int tid = threadIdx.x, lane = tid & 63, wid = tid >> 6;
  int lr = lane & 15, lk = lane >> 4;
  const unsigned short* Qb = Q + (size_t)bh * S_ * D_;
  const unsigned short* Kb = K + (size_t)bh * S_ * D_;
  const unsigned short* VTb = VT + (size_t)bh * S_ * D_;
  unsigned short* Pw = SMEM + 32768 + wid * 640;

  int kr  = tid >> 3, kc8 = tid & 7;
  int kcs = kc8 ^ (kr & 7);
  short8 qf[2][2];
  #pragma unroll
  for (int s = 0; s < 2; ++s) {
    int q0 = (qh*2 + s)*128 + wid*16;
    qf[s][0] = *(const short8*)(Qb + (size_t)(q0 + lr)*D_ + lk*8);
    qf[s][1] = *(const short8*)(Qb + (size_t)(q0 + lr)*D_ + 32 + lk*8);
  }
  {
    unsigned short* Kd = SMEM;
    #pragma unroll
    for (int j = 0; j < 2; ++j) {
      int idx = j*512 + tid;
      GLD16(Kb + (size_t)(kr + j*64)*D_ + kcs*8, &Kd[idx*8]);
    }
  }
  {
    unsigned short* Vd = SMEM + 16384;
    #pragma unroll
    for (int j = 0; j < 2; ++j) {
      int idx = j*512 + tid;
      int d = idx >> 4, c16 = idx & 15;
      int cds = c16 ^ (d & 15);
      GLD16(VTb + (size_t)d*S_ + cds*8, &Vd[idx*8]);
    }
  }
  __syncthreads();

  f32x4 oacc[2][4] = {};
  float plsum[2][4] = {{0.f,0.f,0.f,0.f},{0.f,0.f,0.f,0.f}};
  int cur = 0;
  for (int kt = 0; kt < 4; ++kt) {
    if (kt < 3) {
      unsigned short* Kd = SMEM + (cur^1)*8192;
      unsigned short* Vd = SMEM + 16384 + (cur^1)*8192;
      #pragma unroll
      for (int j = 0; j < 2; ++j) {
        int idx = j*512 + tid;
        int r = idx >> 3, c8 = idx & 7;
        GLD16(Kb + (size_t)((kt+1)*128 + r)*D_ + (c8 ^ (r & 7))*8, &Kd[idx*8]);
        int d = idx >> 4, c16 = idx & 15;
        GLD16(VTb + (size_t)d*S_ + (kt+1)*128 + (c16 ^ (d & 15))*8, &Vd[idx*8]);
      }
    }
    const unsigned short* Kl = SMEM + cur*8192;
    const unsigned short* Vl = SMEM + 16384 + cur*8192;
    #pragma unroll
    for (int s = 0; s < 2; ++s) {
      #pragma unroll
      for (int c = 0; c < 4; ++c) {
        f32x4 s0 = {}, s1 = {};
        {
          const unsigned short* kr0 = &Kl[((2*c)*16 + lr)*64];
          const unsigned short* kr1 = &Kl[((2*c+1)*16 + lr)*64];
          int a0 = ((lk     ^ (lr & 7)))*8;
          int a1 = (((4+lk) ^ (lr & 7)))*8;
          s0 = mfma16(qf[s][0], *(const short8*)(kr0 + a0), s0);
          s0 = mfma16(qf[s][1], *(const short8*)(kr0 + a1), s0);
          s1 = mfma16(qf[s][0], *(const short8*)(kr1 + a0), s1);
          s1 = mfma16(qf[s][1], *(const short8*)(kr1 + a1), s1);
        }
        #pragma unroll
        for (int j = 0; j < 4; ++j) {
          s0[j] = __expf(s0[j] * 0.125f);
          s1[j] = __expf(s1[j] * 0.125f);
          plsum[s][j] += s0[j] + s1[j];
        }
        #pragma unroll
        for (int j = 0; j < 4; ++j) {
          Pw[(lk*4 + j)*40 + lr]      = f2bf(s0[j]);
          Pw[(lk*4 + j)*40 + 16 + lr] = f2bf(s1[j]);
        }
        asm volatile("s_waitcnt lgkmcnt(0)" ::: "memory");
        short8 pf = *(const short8*)&Pw[lr*40 + lk*8];
        #pragma unroll
        for (int dt = 0; dt < 4; ++dt) {
          int drow = dt*16 + lr;
          short8 vf = *(const short8*)&Vl[drow*128 + (((c*4 + lk) ^ lr))*8];
          oacc[s][dt] = mfma16(pf, vf, oacc[s][dt]);
        }
      }
    }
    __syncthreads();
    cur ^= 1;
  }
  #pragma unroll
  for (int s = 0; s < 2; ++s) {
    float lsum[4];
    #pragma unroll
    for (int j = 0; j < 4; ++j) {
      float t = plsum[s][j];
      #pragma unroll
      for (int m = 1; m < 16; m <<= 1) t += __shfl_xor(t, m);
      lsum[j] = t;
    }
    int q0 = (qh*2 + s)*128 + wid*16;
    #pragma unroll
    for (int dt = 0; dt < 4; ++dt)
      #pragma unroll
      for (int j = 0; j < 4; ++j)
        O[(size_t)bh*S_*D_ + (size_t)(q0 + lk*4 + j)*D_ + dt*16 + lr] =
          f2bf(oacc[s][dt][j] / lsum[j]);
  }
}

// ---------------- residual + layernorm: all-bf16 stream, f32 internal ----------------
template<bool PERM>
__global__ __launch_bounds__(256)
void ln_k(const unsigned short* __restrict__ g, unsigned short* __restrict__ x,
          const float* __restrict__ gamma, const float* __restrict__ beta)
{
  int row = blockIdx.x;
  int tid = threadIdx.x;
  int e0 = tid * 4;
  ushort4v gu;
  if (PERM) {
    int b = row >> 9, s = row & 511;
    int h = e0 >> 6, d = e0 & 63;
    gu = *(const ushort4v*)&g[(((size_t)(b*H_ + h)*S_) + s)*D_ + d];
  } else {
    gu = *(const ushort4v*)&g[(size_t)row*E_ + e0];
  }
  ushort4v xu = *(const ushort4v*)&x[(size_t)row*E_ + e0];
  f32x4 v;
  #pragma unroll
  for (int i = 0; i < 4; ++i) v[i] = bf2f(gu[i]) + bf2f(xu[i]);
  float sum = v[0]+v[1]+v[2]+v[3];
  float sq  = v[0]*v[0]+v[1]*v[1]+v[2]*v[2]+v[3]*v[3];
  #pragma unroll
  for (int m = 1; m < 64; m <<= 1) { sum += __shfl_xor(sum, m); sq += __shfl_xor(sq, m); }
  __shared__ float red[2][4];
  int lane = tid & 63, wid = tid >> 6;
  if (lane == 0) { red[0][wid] = sum; red[1][wid] = sq; }
  __syncthreads();
  float ts = red[0][0]+red[0][1]+red[0][2]+red[0][3];
  float tq = red[1][0]+red[1][1]+red[1][2]+red[1][3];
  float mu = ts * (1.0f/E_);
  float var = tq * (1.0f/E_) - mu*mu;
  float rsq = rsqrtf(var + 1e-5f);
  ushort4v yb;
  #pragma unroll
  for (int i = 0; i < 4; ++i)
    yb[i] = f2bf((v[i]-mu)*rsq*gamma[e0+i] + beta[e0+i]);
  *(ushort4v*)&x[(size_t)row*E_ + e0] = yb;
}

// ---------------- output head (bf16 x input, f32 accum) ----------------
__global__ __launch_bounds__(256)
void outp_k(const unsigned short* __restrict__ x, const float* __restrict__ wout,
            float* __restrict__ part)
{
  int b = blockIdx.y;
  int chunk = blockIdx.x;
  int tid = threadIdx.x;
  float acc[OUT_] = {};
  const unsigned short* xr = x + (size_t)b * S_ * E_;
  for (int j = 0; j < 32; ++j) {
    int k = chunk*8192 + j*256 + tid;
    float xv = bf2f(xr[k]);
    const float* wr = wout + (size_t)k * OUT_;
    #pragma unroll
    for (int o = 0; o < OUT_; ++o) acc[o] += xv * wr[o];
  }
  #pragma unroll
  for (int o = 0; o < OUT_; ++o)
    #pragma unroll
    for (int m = 1; m < 64; m <<= 1) acc[o] += __shfl_xor(acc[o], m);
  __shared__ float red[4][OUT_];
  int lane = tid & 63, wid = tid >> 6;
  if (lane == 0) {
    #pragma unroll
    for (int o = 0; o < OUT_; ++o) red[wid][o] = acc[o];
  }
  __syncthreads();
  if (tid < OUT_) {
    float s = red[0][tid] + red[1][tid] + red[2][tid] + red[3][tid];
    part[((size_t)chunk*B_ + b)*OUT_ + tid] = s;
  }
}

__global__ __launch_bounds__(192)
void outred_k(const float* __restrict__ part, const float* __restrict__ bout,
              float* __restrict__ out)
{
  int t = threadIdx.x;
  if (t < B_*OUT_) {
    int b = t / OUT_, o = t % OUT_;
    float s = 0.f;
    for (int c = 0; c < 64; ++c) s += part[((size_t)c*B_ + b)*OUT_ + o];
    s += bout[o];
    out[t] = s;
  }
}

extern "C" void kernel_launch(void* const* d_in, const int* in_sizes, int n_in,
                              void* d_out, int out_size, void* d_ws, size_t ws_size,
                              hipStream_t stream)
{
  (void)out_size;
  float* outb = (float*)d_out;

  static const int expect[14] = {8192, 16384, 1048576, 1024, 1048576, 1024,
                                 1048576, 1024, 1048576, 1024, 1024, 1024,
                                 5242880, 10};
  if (n_in != 14) { code_k<<<dim3(1), dim3(192), 0, stream>>>(outb, 9000.0f); return; }
  for (int i = 0; i < 14; ++i)
    if (in_sizes[i] != expect[i]) {
      code_k<<<dim3(1), dim3(192), 0, stream>>>(outb, 5000.0f + 100.0f*i); return;
    }

  const int* tok = (const int*)d_in[0];
  const float* emb  = (const float*)d_in[1];
  const float* wq   = (const float*)d_in[2];
  const float* bq   = (const float*)d_in[3];
  const float* wk   = (const float*)d_in[4];
  const float* bk   = (const float*)d_in[5];
  const float* wv   = (const float*)d_in[6];
  const float* bv   = (const float*)d_in[7];
  const float* wfc  = (const float*)d_in[8];
  const float* bfc  = (const float*)d_in[9];
  const float* gam  = (const float*)d_in[10];
  const float* bet  = (const float*)d_in[11];
  const float* wout = (const float*)d_in[12];
  const float* bout = (const float*)d_in[13];

  char* ws = (char*)d_ws;
  size_t off = 0;
  unsigned short* wT = (unsigned short*)(ws + off); off += (size_t)4*E_*E_*2;
  unsigned short* x  = (unsigned short*)(ws + off); off += (size_t)M_*E_*2;
  unsigned short* qkvb = (unsigned short*)(ws + off); off += (size_t)3*M_*E_*2;
  unsigned short* gb = (unsigned short*)(ws + off); off += (size_t)M_*E_*2;
  float* part = (float*)(ws + off);                 off += (size_t)64*B_*OUT_*4;
  if (off > ws_size) { code_k<<<dim3(1), dim3(192), 0, stream>>>(outb, 9500.0f); return; }

  transpose_k<<<dim3(16,16,4), dim3(64,4), 0, stream>>>(wq, wk, wv, wfc, wT);
  embed_k<<<dim3(M_), dim3(256), 0, stream>>>(tok, emb, x);
  unsigned short* qb = qkvb;
  unsigned short* kb = qkvb + (size_t)M_*E_;
  unsigned short* vb = qkvb + (size_t)2*M_*E_;   // VT [B,H,D,S]
  for (int l = 0; l < NL_; ++l) {
    gemm_bt_k<0><<<dim3(64,16), dim3(256), 0, stream>>>(x, wT, bq, bk, qkvb);
    gemm_bt_k<2><<<dim3(64,8),  dim3(256), 0, stream>>>(x, wT + (size_t)2*E_*E_, bv, bv, vb);
    attn_k<<<dim3(512), dim3(512), 75776, stream>>>(qb, kb, vb, gb);
    ln_k<true><<<dim3(M_), dim3(256), 0, stream>>>(gb, x, gam, bet);
    gemm_bt_k<1><<<dim3(64,8), dim3(256), 0, stream>>>(x, wT + (size_t)3*E_*E_, bfc, bfc, gb);
    ln_k<false><<<dim3(M_), dim3(256), 0, stream>>>(gb, x, gam, bet);
  }
  outp_k<<<dim3(64,B_), dim3(256), 0, stream>>>(x, wout, part);
  outred_k<<<dim3(1), dim3(192), 0, stream>>>(part, bout, outb);
}